// Round 3
// baseline (99.906 us; speedup 1.0000x reference)
//
#include <hip/hip_runtime.h>

#define BIGF 1e10f
#define HH 256
#define WW 256
#define BB 4
#define NPIX (BB * HH * WW)
#define COLS_GRID (BB * 128)

// ws layout (bytes):
//   [0 .. 31]   int flags[8] : pred_any[4], target_any[4]
//   [64 .. 71]  double acc
//   [80 .. 83]  unsigned done-counter
//   [128 .. )   u32 F1p[2][BB][HH][WW] : packed row-EDT^2 (lo16=dist2-to-fg, hi16=dist2-to-bg, 0xFFFF=BIG)
#define WS_FLAGS_OFF 0
#define WS_ACC_OFF 64
#define WS_CNT_OFF 80
#define WS_F1_OFF 128

// nearest set bit distance in a 256-bit mask (words M[0..3], bit p = 64w+lane),
// searching both directions from x. Returns > 255 if mask empty.
__device__ inline int nearest_set_dist(const unsigned long long* M, int x) {
    int wx = x >> 6, bx = x & 63;
    int dl = 1 << 20, dr = 1 << 20;
    unsigned long long t = M[wx] & (bx == 63 ? ~0ULL : ((1ULL << (bx + 1)) - 1ULL));
    int w = wx;
    while (true) {
        if (t) { int p = (w << 6) + 63 - __builtin_clzll(t); dl = x - p; break; }
        if (--w < 0) break;
        t = M[w];
    }
    t = M[wx] & (~0ULL << bx);
    w = wx;
    while (true) {
        if (t) { int p = (w << 6) + __builtin_ctzll(t); dr = p - x; break; }
        if (++w > 3) break;
        t = M[w];
    }
    return dl < dr ? dl : dr;
}

// Kernel A: per-(img,b,y) row. Ballot fg mask; exact 1D row-EDT^2 to nearest fg and
// nearest bg via bit scans, packed u32 per pixel. Also atomicOr per-(img,b) any-fg flag.
__global__ void hdt_rows_kernel(const float* __restrict__ pred,
                                const float* __restrict__ tgt,
                                unsigned* __restrict__ F1p,
                                int* __restrict__ flags) {
    int blk = blockIdx.x;          // img*1024 + b*256 + y
    int y = blk & (HH - 1);
    int b = (blk >> 8) & 3;
    int img = blk >> 10;
    const float* src = (img ? tgt : pred) + (b * HH + y) * WW;
    int x = threadIdx.x;
    bool fg = src[x] > 0.5f;
    unsigned long long bal = __ballot(fg);
    __shared__ unsigned long long mfg[4];
    if ((x & 63) == 0) mfg[x >> 6] = bal;
    __syncthreads();
    unsigned long long M0 = mfg[0], M1 = mfg[1], M2 = mfg[2], M3 = mfg[3];
    if (x == 0 && (M0 | M1 | M2 | M3))
        atomicOr(&flags[img * 4 + b], 1);
    unsigned long long Mfg[4] = {M0, M1, M2, M3};
    unsigned long long Mbg[4] = {~M0, ~M1, ~M2, ~M3};
    int dfg = nearest_set_dist(Mfg, x);  // dist to nearest fg pixel in row
    int dbg = nearest_set_dist(Mbg, x);  // dist to nearest bg pixel in row
    unsigned lo = (dfg > 255) ? 0xFFFFu : (unsigned)(dfg * dfg);
    unsigned hi = (dbg > 255) ? 0xFFFFu : (unsigned)(dbg * dbg);
    F1p[((img * BB + b) * HH + y) * WW + x] = lo | (hi << 16);
}

__device__ inline float col_search(const unsigned* __restrict__ col, int y, bool cfg) {
    // query pixel class cfg: fg -> need dist-to-bg (hi16); bg -> dist-to-fg (lo16)
    unsigned v0 = col[y];
    unsigned u0 = cfg ? (v0 >> 16) : (v0 & 0xFFFFu);
    float best = (u0 == 0xFFFFu) ? BIGF : (float)u0;
    for (int s = 1; s < HH; ++s) {
        float ss = (float)(s * s);
        if (ss >= best) break;    // all farther candidates >= s^2 >= best (exact)
        int ym = y - s, yp = y + s;
        if (ym >= 0) {
            unsigned v = col[ym];
            unsigned u = cfg ? (v >> 16) : (v & 0xFFFFu);
            float f = (u == 0xFFFFu) ? BIGF : (float)u;
            best = fminf(best, f + ss);
        }
        if (yp < HH) {
            unsigned v = col[yp];
            unsigned u = cfg ? (v >> 16) : (v & 0xFFFFu);
            float f = (u == 0xFFFFu) ? BIGF : (float)u;
            best = fminf(best, f + ss);
        }
    }
    return best;
}

// Kernel B: per-(b, 2-column tile). Stage packed columns in LDS, exact expanding-window
// min-plus along H with class selection, fused loss + block reduce + last-block finalize.
__launch_bounds__(256)
__global__ void hdt_cols_loss_kernel(const float* __restrict__ pred,
                                     const float* __restrict__ tgt,
                                     const unsigned* __restrict__ F1p,
                                     const int* __restrict__ flags,
                                     double* __restrict__ acc,
                                     unsigned* __restrict__ cnt,
                                     float* __restrict__ out) {
    int blk = blockIdx.x;          // b*128 + tile
    int b = blk >> 7;
    int x0 = (blk & 127) * 2;
    __shared__ unsigned S[2][2][HH];   // [img][xi][y]  4 KB
    int tid = threadIdx.x;             // = y
    {
        const uint2* p0 = (const uint2*)(F1p + ((0 * BB + b) * HH + tid) * WW + x0);
        const uint2* p1 = (const uint2*)(F1p + ((1 * BB + b) * HH + tid) * WW + x0);
        uint2 a = *p0, c = *p1;
        S[0][0][tid] = a.x; S[0][1][tid] = a.y;
        S[1][0][tid] = c.x; S[1][1][tid] = c.y;
    }
    __syncthreads();
    int y = tid;
    int fl_p = flags[b], fl_t = flags[4 + b];
    float lsum = 0.0f;
    #pragma unroll
    for (int k = 0; k < 2; ++k) {
        int x = x0 + k;
        int idx = (b * HH + y) * WW + x;
        float pv = pred[idx], tv = tgt[idx];
        float d2p = 0.0f, d2t = 0.0f;
        if (fl_p) {
            float best = col_search(S[0][k], y, pv > 0.5f);
            float dt = sqrtf(fminf(best, BIGF));
            d2p = dt * dt;
        }
        if (fl_t) {
            float best = col_search(S[1][k], y, tv > 0.5f);
            float dt = sqrtf(fminf(best, BIGF));
            d2t = dt * dt;
        }
        float e = pv - tv;
        lsum += e * e * (d2p + d2t);
    }
    // block reduce: wave64 shuffle then LDS across 4 waves
    #pragma unroll
    for (int off = 32; off > 0; off >>= 1)
        lsum += __shfl_down(lsum, off, 64);
    __shared__ float wsum[4];
    int lane = tid & 63, wv = tid >> 6;
    if (lane == 0) wsum[wv] = lsum;
    __syncthreads();
    if (tid == 0) {
        float s2 = wsum[0] + wsum[1] + wsum[2] + wsum[3];
        atomicAdd(acc, (double)s2);
        __threadfence();
        if (atomicAdd(cnt, 1u) == COLS_GRID - 1) {
            double v = atomicAdd(acc, 0.0);   // device-coherent read of final sum
            out[0] = (float)(v * (1.0 / (double)NPIX));
        }
    }
}

extern "C" void kernel_launch(void* const* d_in, const int* in_sizes, int n_in,
                              void* d_out, int out_size, void* d_ws, size_t ws_size,
                              hipStream_t stream) {
    const float* pred = (const float*)d_in[0];
    const float* tgt = (const float*)d_in[1];
    float* out = (float*)d_out;
    char* ws = (char*)d_ws;
    int* flags = (int*)(ws + WS_FLAGS_OFF);
    double* acc = (double*)(ws + WS_ACC_OFF);
    unsigned* cnt = (unsigned*)(ws + WS_CNT_OFF);
    unsigned* F1p = (unsigned*)(ws + WS_F1_OFF);

    hipMemsetAsync(ws, 0, 128, stream);  // zero flags + acc + counter
    hdt_rows_kernel<<<2 * BB * HH, WW, 0, stream>>>(pred, tgt, F1p, flags);
    hdt_cols_loss_kernel<<<COLS_GRID, 256, 0, stream>>>(pred, tgt, F1p, flags, acc, cnt, out);
}

// Round 4
// 86.659 us; speedup vs baseline: 1.1529x; 1.1529x over previous
//
#include <hip/hip_runtime.h>

#define BIGF 1e10f
#define HH 256
#define WW 256
#define BB 4
#define NPIX (BB * HH * WW)
#define COLS_GRID (BB * WW)

// ws layout (bytes):
//   [0  .. 7  ]  double acc
//   [16 .. 19 ]  unsigned done-counter
//   [64 .. 64+8K)   int rowany[2][BB][HH]   (per-row any-fg, per image)
//   [16384 .. )     uint4 R[BB][WW][HH]     transposed per-pixel record:
//                   .x = pred row-EDT^2 packed (lo16 dist2-to-fg, hi16 dist2-to-bg, 0xFFFF=BIG)
//                   .y = tgt  row-EDT^2 packed (same)
//                   .z = bit-pattern of (pred-tgt)^2
//                   .w = class bits (b0: pred>0.5, b1: tgt>0.5)
#define WS_ACC_OFF 0
#define WS_CNT_OFF 16
#define WS_ROWANY_OFF 64
#define WS_R_OFF 16384

// nearest set bit distance in a 256-bit mask (words M[0..3], bit p = 64w+lane),
// searching both directions from x. Returns > 255 if mask empty.
__device__ inline int nearest_set_dist(const unsigned long long* M, int x) {
    int wx = x >> 6, bx = x & 63;
    int dl = 1 << 20, dr = 1 << 20;
    unsigned long long t = M[wx] & (bx == 63 ? ~0ULL : ((1ULL << (bx + 1)) - 1ULL));
    int w = wx;
    while (true) {
        if (t) { int p = (w << 6) + 63 - __builtin_clzll(t); dl = x - p; break; }
        if (--w < 0) break;
        t = M[w];
    }
    t = M[wx] & (~0ULL << bx);
    w = wx;
    while (true) {
        if (t) { int p = (w << 6) + __builtin_ctzll(t); dr = p - x; break; }
        if (++w > 3) break;
        t = M[w];
    }
    return dl < dr ? dl : dr;
}

__device__ inline unsigned pack_d2(int dfg, int dbg) {
    unsigned lo = (dfg > 255) ? 0xFFFFu : (unsigned)(dfg * dfg);
    unsigned hi = (dbg > 255) ? 0xFFFFu : (unsigned)(dbg * dbg);
    return lo | (hi << 16);
}

// Kernel A: one block per (b,y) row, thread = x. Both images in one pass.
// Exact 1D row EDT^2 via ballot + bit scans; emits transposed 16B record per pixel.
__global__ void hdt_rows_kernel(const float* __restrict__ pred,
                                const float* __restrict__ tgt,
                                uint4* __restrict__ R,
                                int* __restrict__ rowany,
                                double* __restrict__ acc,
                                unsigned* __restrict__ cnt) {
    int blk = blockIdx.x;          // b*HH + y
    int y = blk & (HH - 1);
    int b = blk >> 8;
    int x = threadIdx.x;
    int idx = (b * HH + y) * WW + x;
    float pv = pred[idx], tv = tgt[idx];
    bool pfg = pv > 0.5f, tfg = tv > 0.5f;
    unsigned long long bp = __ballot(pfg);
    unsigned long long bt = __ballot(tfg);
    __shared__ unsigned long long mp[4], mt[4];
    if ((x & 63) == 0) { mp[x >> 6] = bp; mt[x >> 6] = bt; }
    __syncthreads();
    unsigned long long Mp[4] = {mp[0], mp[1], mp[2], mp[3]};
    unsigned long long Mt[4] = {mt[0], mt[1], mt[2], mt[3]};
    if (x == 0) {
        rowany[(0 * BB + b) * HH + y] = (Mp[0] | Mp[1] | Mp[2] | Mp[3]) ? 1 : 0;
        rowany[(1 * BB + b) * HH + y] = (Mt[0] | Mt[1] | Mt[2] | Mt[3]) ? 1 : 0;
        if (blk == 0) { *acc = 0.0; *cnt = 0u; }  // replaces the memset dispatch
    }
    unsigned long long Mpn[4] = {~Mp[0], ~Mp[1], ~Mp[2], ~Mp[3]};
    unsigned long long Mtn[4] = {~Mt[0], ~Mt[1], ~Mt[2], ~Mt[3]};
    int dpf = nearest_set_dist(Mp, x);   // pred: dist to nearest fg in row
    int dpb = nearest_set_dist(Mpn, x);  // pred: dist to nearest bg in row
    int dtf = nearest_set_dist(Mt, x);
    int dtb = nearest_set_dist(Mtn, x);
    float e = pv - tv;
    uint4 rec;
    rec.x = pack_d2(dpf, dpb);
    rec.y = pack_d2(dtf, dtb);
    rec.z = __float_as_uint(e * e);
    rec.w = (pfg ? 1u : 0u) | (tfg ? 2u : 0u);
    R[(b * WW + x) * HH + y] = rec;      // transposed store; L2 merges across y-blocks
}

// Kernel B: one block per (b,x) column, thread = y. One coalesced uint4 load/thread,
// exact expanding-window min-plus along H with class selection, fused loss +
// block reduce + last-block finalize.
__launch_bounds__(256)
__global__ void hdt_cols_kernel(const uint4* __restrict__ R,
                                const int* __restrict__ rowany,
                                double* __restrict__ acc,
                                unsigned* __restrict__ cnt,
                                float* __restrict__ out) {
    int blk = blockIdx.x;          // b*WW + x
    int b = blk >> 8;
    int y = threadIdx.x;
    __shared__ float S[4][HH];     // p_fg, p_bg, t_fg, t_bg  (4 KB)
    uint4 rec = R[blk * HH + y];
    unsigned pp = rec.x, tp = rec.y;
    float errsq = __uint_as_float(rec.z);
    bool pfg = (rec.w & 1u) != 0u, tfg = (rec.w & 2u) != 0u;
    {
        unsigned a = pp & 0xFFFFu, c = pp >> 16, d = tp & 0xFFFFu, g = tp >> 16;
        S[0][y] = (a == 0xFFFFu) ? BIGF : (float)a;
        S[1][y] = (c == 0xFFFFu) ? BIGF : (float)c;
        S[2][y] = (d == 0xFFFFu) ? BIGF : (float)d;
        S[3][y] = (g == 0xFFFFu) ? BIGF : (float)g;
    }
    // per-(img,b) any-fg flags from rowany (coalesced loads + ballots)
    unsigned long long ap = __ballot(rowany[(0 * BB + b) * HH + y] != 0);
    unsigned long long at = __ballot(rowany[(1 * BB + b) * HH + y] != 0);
    __shared__ unsigned wfl[4];
    if ((y & 63) == 0)
        wfl[y >> 6] = ((ap != 0ULL) ? 1u : 0u) | ((at != 0ULL) ? 2u : 0u);
    __syncthreads();
    unsigned fl = wfl[0] | wfl[1] | wfl[2] | wfl[3];

    float d2p = 0.0f, d2t = 0.0f;
    if (fl & 1u) {
        const float* col = pfg ? S[1] : S[0];  // fg query -> dist-to-bg half
        float best = col[y];
        for (int s = 1; s < HH; ++s) {
            float ss = (float)(s * s);
            if (ss >= best) break;             // exact: skipped cands >= s^2 >= best
            int ym = y - s, yp = y + s;
            if (ym >= 0) best = fminf(best, col[ym] + ss);
            if (yp < HH) best = fminf(best, col[yp] + ss);
        }
        float dt = sqrtf(fminf(best, BIGF));
        d2p = dt * dt;
    }
    if (fl & 2u) {
        const float* col = tfg ? S[3] : S[2];
        float best = col[y];
        for (int s = 1; s < HH; ++s) {
            float ss = (float)(s * s);
            if (ss >= best) break;
            int ym = y - s, yp = y + s;
            if (ym >= 0) best = fminf(best, col[ym] + ss);
            if (yp < HH) best = fminf(best, col[yp] + ss);
        }
        float dt = sqrtf(fminf(best, BIGF));
        d2t = dt * dt;
    }
    float lsum = errsq * (d2p + d2t);

    #pragma unroll
    for (int off = 32; off > 0; off >>= 1)
        lsum += __shfl_down(lsum, off, 64);
    __shared__ float wsum[4];
    if ((y & 63) == 0) wsum[y >> 6] = lsum;
    __syncthreads();
    if (y == 0) {
        float s2 = wsum[0] + wsum[1] + wsum[2] + wsum[3];
        atomicAdd(acc, (double)s2);
        __threadfence();
        if (atomicAdd(cnt, 1u) == COLS_GRID - 1) {
            double v = atomicAdd(acc, 0.0);    // device-coherent final read
            out[0] = (float)(v * (1.0 / (double)NPIX));
        }
    }
}

extern "C" void kernel_launch(void* const* d_in, const int* in_sizes, int n_in,
                              void* d_out, int out_size, void* d_ws, size_t ws_size,
                              hipStream_t stream) {
    const float* pred = (const float*)d_in[0];
    const float* tgt = (const float*)d_in[1];
    float* out = (float*)d_out;
    char* ws = (char*)d_ws;
    double* acc = (double*)(ws + WS_ACC_OFF);
    unsigned* cnt = (unsigned*)(ws + WS_CNT_OFF);
    int* rowany = (int*)(ws + WS_ROWANY_OFF);
    uint4* R = (uint4*)(ws + WS_R_OFF);

    hdt_rows_kernel<<<BB * HH, WW, 0, stream>>>(pred, tgt, R, rowany, acc, cnt);
    hdt_cols_kernel<<<COLS_GRID, 256, 0, stream>>>(R, rowany, acc, cnt, out);
}

// Round 5
// 76.007 us; speedup vs baseline: 1.3144x; 1.1402x over previous
//
#include <hip/hip_runtime.h>

#define BIGF 1e10f
#define HH 256
#define WW 256
#define BB 4
#define NPIX (BB * HH * WW)
#define COLS_GRID (BB * (WW / 2))   // 512 blocks, 2 columns each

// ws layout (bytes):
//   [0 .. 511]   double acc bins, one per 64 B (acc[i] at byte i*64) -- distinct L2 lines
//   [512 .. 515] unsigned done-counter
//   [1024 .. 1024+8K)  int rowany[2][BB][HH]  (per-row any-fg, per image)
//   [16384 .. )  uint4 R[BB][WW][HH] transposed per-pixel record:
//                .x = pred row-EDT^2 packed (lo16 dist2-to-fg, hi16 dist2-to-bg, 0xFFFF=BIG)
//                .y = tgt  row-EDT^2 packed (same)
//                .z = bit-pattern of (pred-tgt)^2
//                .w = class bits (b0: pred>0.5, b1: tgt>0.5)
#define WS_ACC_OFF 0
#define WS_CNT_OFF 512
#define WS_ROWANY_OFF 1024
#define WS_R_OFF 16384
#define ACC_STRIDE 8   // doubles: 8 doubles = 64 B apart

// nearest set bit distance in a 256-bit mask (words M[0..3], bit p = 64w+lane),
// searching both directions from x. Returns > 255 if mask empty.
__device__ inline int nearest_set_dist(const unsigned long long* M, int x) {
    int wx = x >> 6, bx = x & 63;
    int dl = 1 << 20, dr = 1 << 20;
    unsigned long long t = M[wx] & (bx == 63 ? ~0ULL : ((1ULL << (bx + 1)) - 1ULL));
    int w = wx;
    while (true) {
        if (t) { int p = (w << 6) + 63 - __builtin_clzll(t); dl = x - p; break; }
        if (--w < 0) break;
        t = M[w];
    }
    t = M[wx] & (~0ULL << bx);
    w = wx;
    while (true) {
        if (t) { int p = (w << 6) + __builtin_ctzll(t); dr = p - x; break; }
        if (++w > 3) break;
        t = M[w];
    }
    return dl < dr ? dl : dr;
}

__device__ inline unsigned pack_d2(int dfg, int dbg) {
    unsigned lo = (dfg > 255) ? 0xFFFFu : (unsigned)(dfg * dfg);
    unsigned hi = (dbg > 255) ? 0xFFFFu : (unsigned)(dbg * dbg);
    return lo | (hi << 16);
}

// Kernel A: one block per (b,y) row, thread = x. Both images in one pass.
// Exact 1D row EDT^2 via ballot + bit scans; emits transposed 16B record per pixel.
__global__ void hdt_rows_kernel(const float* __restrict__ pred,
                                const float* __restrict__ tgt,
                                uint4* __restrict__ R,
                                int* __restrict__ rowany,
                                double* __restrict__ acc,
                                unsigned* __restrict__ cnt) {
    int blk = blockIdx.x;          // b*HH + y
    int y = blk & (HH - 1);
    int b = blk >> 8;
    int x = threadIdx.x;
    int idx = (b * HH + y) * WW + x;
    float pv = pred[idx], tv = tgt[idx];
    bool pfg = pv > 0.5f, tfg = tv > 0.5f;
    unsigned long long bp = __ballot(pfg);
    unsigned long long bt = __ballot(tfg);
    __shared__ unsigned long long mp[4], mt[4];
    if ((x & 63) == 0) { mp[x >> 6] = bp; mt[x >> 6] = bt; }
    __syncthreads();
    unsigned long long Mp[4] = {mp[0], mp[1], mp[2], mp[3]};
    unsigned long long Mt[4] = {mt[0], mt[1], mt[2], mt[3]};
    if (x == 0) {
        rowany[(0 * BB + b) * HH + y] = (Mp[0] | Mp[1] | Mp[2] | Mp[3]) ? 1 : 0;
        rowany[(1 * BB + b) * HH + y] = (Mt[0] | Mt[1] | Mt[2] | Mt[3]) ? 1 : 0;
        if (blk == 0) {                 // replaces the memset dispatch
            #pragma unroll
            for (int i = 0; i < 8; ++i) acc[i * ACC_STRIDE] = 0.0;
            *cnt = 0u;
        }
    }
    unsigned long long Mpn[4] = {~Mp[0], ~Mp[1], ~Mp[2], ~Mp[3]};
    unsigned long long Mtn[4] = {~Mt[0], ~Mt[1], ~Mt[2], ~Mt[3]};
    int dpf = nearest_set_dist(Mp, x);   // pred: dist to nearest fg in row
    int dpb = nearest_set_dist(Mpn, x);  // pred: dist to nearest bg in row
    int dtf = nearest_set_dist(Mt, x);
    int dtb = nearest_set_dist(Mtn, x);
    float e = pv - tv;
    uint4 rec;
    rec.x = pack_d2(dpf, dpb);
    rec.y = pack_d2(dtf, dtb);
    rec.z = __float_as_uint(e * e);
    rec.w = (pfg ? 1u : 0u) | (tfg ? 2u : 0u);
    R[(b * WW + x) * HH + y] = rec;      // transposed store (scatter lives on write side)
}

// Exact expanding-window min-plus along the column, chunked x4, branchless bounds.
// Extra in-chunk candidates are valid candidates (never changes the min); the exit
// check skips only candidates with s^2 >= best, so the result is bitwise exact.
__device__ inline float col_search(const float* __restrict__ col, int y) {
    float best = col[y];
    #pragma unroll 1
    for (int s = 1; s < HH; s += 4) {
        if ((float)(s * s) >= best) break;
        #pragma unroll
        for (int k = 0; k < 4; ++k) {
            int sk = s + k;
            float ss = (float)(sk * sk);
            int ym = y - sk, yp = y + sk;
            float a = col[ym & (HH - 1)];
            float c = col[yp & (HH - 1)];
            a = (ym >= 0) ? a : BIGF;
            c = (yp < HH) ? c : BIGF;
            best = fminf(best, fminf(a, c) + ss);
        }
    }
    return best;
}

// Kernel B: one block per (b, 2-column tile), thread = y. Two coalesced uint4
// loads/thread, exact column search with class selection, fused loss +
// block reduce + 8-bin atomics + last-block finalize.
__launch_bounds__(256)
__global__ void hdt_cols_kernel(const uint4* __restrict__ R,
                                const int* __restrict__ rowany,
                                double* __restrict__ acc,
                                unsigned* __restrict__ cnt,
                                float* __restrict__ out) {
    int blk = blockIdx.x;          // b*128 + xt
    int b = blk >> 7;
    int x0 = (blk & 127) << 1;
    int y = threadIdx.x;
    __shared__ float S[2][4][HH];  // [xi][p_fg,p_bg,t_fg,t_bg][y]  8 KB
    uint4 r0 = R[(b * WW + x0) * HH + y];
    uint4 r1 = R[(b * WW + x0 + 1) * HH + y];
    {
        unsigned a = r0.x & 0xFFFFu, c = r0.x >> 16, d = r0.y & 0xFFFFu, g = r0.y >> 16;
        S[0][0][y] = (a == 0xFFFFu) ? BIGF : (float)a;
        S[0][1][y] = (c == 0xFFFFu) ? BIGF : (float)c;
        S[0][2][y] = (d == 0xFFFFu) ? BIGF : (float)d;
        S[0][3][y] = (g == 0xFFFFu) ? BIGF : (float)g;
        a = r1.x & 0xFFFFu; c = r1.x >> 16; d = r1.y & 0xFFFFu; g = r1.y >> 16;
        S[1][0][y] = (a == 0xFFFFu) ? BIGF : (float)a;
        S[1][1][y] = (c == 0xFFFFu) ? BIGF : (float)c;
        S[1][2][y] = (d == 0xFFFFu) ? BIGF : (float)d;
        S[1][3][y] = (g == 0xFFFFu) ? BIGF : (float)g;
    }
    // per-(img,b) any-fg flags from rowany (coalesced loads + ballots)
    unsigned long long ap = __ballot(rowany[(0 * BB + b) * HH + y] != 0);
    unsigned long long at = __ballot(rowany[(1 * BB + b) * HH + y] != 0);
    __shared__ unsigned wfl[4];
    if ((y & 63) == 0)
        wfl[y >> 6] = ((ap != 0ULL) ? 1u : 0u) | ((at != 0ULL) ? 2u : 0u);
    __syncthreads();
    unsigned fl = wfl[0] | wfl[1] | wfl[2] | wfl[3];

    float lsum = 0.0f;
    {
        float d2p = 0.0f, d2t = 0.0f;
        if (fl & 1u) {
            float bp = col_search(S[0][(r0.w & 1u) ? 1 : 0], y);
            float dt = sqrtf(fminf(bp, BIGF));
            d2p = dt * dt;
        }
        if (fl & 2u) {
            float bt = col_search(S[0][(r0.w & 2u) ? 3 : 2], y);
            float dt = sqrtf(fminf(bt, BIGF));
            d2t = dt * dt;
        }
        lsum += __uint_as_float(r0.z) * (d2p + d2t);
    }
    {
        float d2p = 0.0f, d2t = 0.0f;
        if (fl & 1u) {
            float bp = col_search(S[1][(r1.w & 1u) ? 1 : 0], y);
            float dt = sqrtf(fminf(bp, BIGF));
            d2p = dt * dt;
        }
        if (fl & 2u) {
            float bt = col_search(S[1][(r1.w & 2u) ? 3 : 2], y);
            float dt = sqrtf(fminf(bt, BIGF));
            d2t = dt * dt;
        }
        lsum += __uint_as_float(r1.z) * (d2p + d2t);
    }

    #pragma unroll
    for (int off = 32; off > 0; off >>= 1)
        lsum += __shfl_down(lsum, off, 64);
    __shared__ float wsum[4];
    if ((y & 63) == 0) wsum[y >> 6] = lsum;
    __syncthreads();
    if (y == 0) {
        float s2 = wsum[0] + wsum[1] + wsum[2] + wsum[3];
        atomicAdd(&acc[(blk & 7) * ACC_STRIDE], (double)s2);
        __threadfence();
        if (atomicAdd(cnt, 1u) == COLS_GRID - 1) {
            double v = 0.0;
            #pragma unroll
            for (int i = 0; i < 8; ++i)
                v += atomicAdd(&acc[i * ACC_STRIDE], 0.0);  // device-coherent reads
            out[0] = (float)(v * (1.0 / (double)NPIX));
        }
    }
}

extern "C" void kernel_launch(void* const* d_in, const int* in_sizes, int n_in,
                              void* d_out, int out_size, void* d_ws, size_t ws_size,
                              hipStream_t stream) {
    const float* pred = (const float*)d_in[0];
    const float* tgt = (const float*)d_in[1];
    float* out = (float*)d_out;
    char* ws = (char*)d_ws;
    double* acc = (double*)(ws + WS_ACC_OFF);
    unsigned* cnt = (unsigned*)(ws + WS_CNT_OFF);
    int* rowany = (int*)(ws + WS_ROWANY_OFF);
    uint4* R = (uint4*)(ws + WS_R_OFF);

    hdt_rows_kernel<<<BB * HH, WW, 0, stream>>>(pred, tgt, R, rowany, acc, cnt);
    hdt_cols_kernel<<<COLS_GRID, 256, 0, stream>>>(R, rowany, acc, cnt, out);
}

// Round 6
// 75.272 us; speedup vs baseline: 1.3273x; 1.0098x over previous
//
#include <hip/hip_runtime.h>

#define BIGF 1e10f
#define HH 256
#define WW 256
#define BB 4
#define NPIX (BB * HH * WW)
#define MAIN_GRID (BB * 64)   // 256 blocks, 4 rows each

// ws layout (bytes):
//   [0 .. 511]    double acc bins, one per 64 B (acc[i*8]) -- distinct L2 lines
//   [512 .. 515]  unsigned done-counter
//   [1024 .. 1024+64K)  u32 gmask[2][BB][HH][8] : fg bit-masks, bit x of row y
#define WS_ACC_OFF 0
#define WS_CNT_OFF 512
#define WS_MASK_OFF 1024
#define ACC_STRIDE 8   // doubles: 64 B apart

// Kernel M: build packed fg masks. grid = 2 img x 4 b x 8 ytiles = 64 blocks x 256.
// Wave w handles 8 rows; per row: 4 coalesced loads + 4 ballots, lane 0 stores 32 B.
__global__ void hdt_masks_kernel(const float* __restrict__ pred,
                                 const float* __restrict__ tgt,
                                 unsigned* __restrict__ gmask,
                                 double* __restrict__ acc,
                                 unsigned* __restrict__ cnt) {
    int blk = blockIdx.x;
    int img = blk >> 5;
    int b = (blk >> 3) & 3;
    int yt = blk & 7;
    int w = threadIdx.x >> 6, lane = threadIdx.x & 63;
    if (blk == 0 && threadIdx.x == 0) {      // replaces a memset dispatch
        #pragma unroll
        for (int i = 0; i < 8; ++i) acc[i * ACC_STRIDE] = 0.0;
        *cnt = 0u;
    }
    const float* base = (img ? tgt : pred) + (b * HH) * WW;
    #pragma unroll 1
    for (int r = 0; r < 8; ++r) {
        int y = yt * 32 + w * 8 + r;
        const float* src = base + y * WW;
        unsigned wds[8];
        #pragma unroll
        for (int q = 0; q < 4; ++q) {
            unsigned long long bal = __ballot(src[(q << 6) + lane] > 0.5f);
            wds[2 * q] = (unsigned)bal;
            wds[2 * q + 1] = (unsigned)(bal >> 32);
        }
        if (lane == 0) {
            uint4* dst = (uint4*)(gmask + ((img * BB + b) * HH + y) * 8);
            dst[0] = make_uint4(wds[0], wds[1], wds[2], wds[3]);
            dst[1] = make_uint4(wds[4], wds[5], wds[6], wds[7]);
        }
    }
}

// Exact 1D distance^2 along a row to the nearest bit of class (mask ^ iv),
// from position x. 8 u32 words per row in LDS; wave-uniform row => broadcast reads.
__device__ inline float row_d2(const unsigned* __restrict__ rm, int x, unsigned iv) {
    int wx = x >> 5, bx = x & 31;
    int dl = 1 << 20, dr = 1 << 20;
    unsigned t = (rm[wx] ^ iv) & (0xFFFFFFFFu >> (31 - bx));   // bits <= bx
    int w = wx;
    while (true) {
        if (t) { int p = (w << 5) + 31 - __builtin_clz(t); dl = x - p; break; }
        if (--w < 0) break;
        t = rm[w] ^ iv;
    }
    t = (rm[wx] ^ iv) & (0xFFFFFFFFu << bx);                    // bits >= bx
    w = wx;
    while (true) {
        if (t) { int p = (w << 5) + __builtin_ctz(t); dr = p - x; break; }
        if (++w > 7) break;
        t = rm[w] ^ iv;
    }
    int d = dl < dr ? dl : dr;
    return (d > 255) ? BIGF : (float)(d * d);
}

// Exact expanding-window min-plus along the column; candidate rows' row-dist^2
// computed on demand by bit scan. Skipped candidates satisfy fl(f+s^2) >= s^2 >= best.
__device__ inline float col_min(const unsigned* __restrict__ mb, int y, int x, unsigned iv) {
    float best = row_d2(mb + y * 8, x, iv);
    #pragma unroll 1
    for (int s = 1; s < HH; ++s) {
        float ss = (float)(s * s);
        if (ss >= best) break;
        int ym = y - s, yp = y + s;
        if (ym >= 0) best = fminf(best, row_d2(mb + ym * 8, x, iv) + ss);
        if (yp < HH) best = fminf(best, row_d2(mb + yp * 8, x, iv) + ss);
    }
    return best;
}

// Kernel C: block = (b, 4-row tile), thread = x. Masks staged in 16 KB LDS,
// flags derived from staged words, fused loss + block reduce + 8-bin atomics
// + last-block finalize.
__launch_bounds__(256)
__global__ void hdt_main_kernel(const float* __restrict__ pred,
                                const float* __restrict__ tgt,
                                const unsigned* __restrict__ gmask,
                                double* __restrict__ acc,
                                unsigned* __restrict__ cnt,
                                float* __restrict__ out) {
    int blk = blockIdx.x;          // b*64 + yt
    int b = blk >> 6;
    int y0 = (blk & 63) << 2;
    int tid = threadIdx.x;
    __shared__ __align__(16) unsigned lmask[2][HH][8];   // 16 KB
    __shared__ unsigned wfl[4];
    {
        int img = tid >> 7, r2 = (tid & 127) << 1;       // 2 rows per thread
        const uint4* gp = (const uint4*)(gmask + ((img * BB + b) * HH + r2) * 8);
        uint4 a0 = gp[0], a1 = gp[1], a2 = gp[2], a3 = gp[3];
        uint4* lp = (uint4*)&lmask[img][r2][0];
        lp[0] = a0; lp[1] = a1; lp[2] = a2; lp[3] = a3;
        unsigned onz = a0.x | a0.y | a0.z | a0.w | a1.x | a1.y | a1.z | a1.w |
                       a2.x | a2.y | a2.z | a2.w | a3.x | a3.y | a3.z | a3.w;
        unsigned long long bal = __ballot(onz != 0u);    // waves 0-1: img0, 2-3: img1
        if ((tid & 63) == 0) wfl[tid >> 6] = (bal != 0ULL) ? 1u : 0u;
    }
    __syncthreads();
    unsigned fl_p = wfl[0] | wfl[1];
    unsigned fl_t = wfl[2] | wfl[3];

    int x = tid;
    float lsum = 0.0f;
    #pragma unroll 1
    for (int r = 0; r < 4; ++r) {
        int y = y0 + r;
        int idx = (b * HH + y) * WW + x;
        float pv = pred[idx], tv = tgt[idx];
        float e = pv - tv;
        float errsq = e * e;
        float d2p = 0.0f, d2t = 0.0f;
        if (fl_p) {
            // query class fg -> scan for bg (invert); bg -> scan for fg
            unsigned iv = (pv > 0.5f) ? 0xFFFFFFFFu : 0u;
            float best = col_min(&lmask[0][0][0], y, x, iv);
            float dt = sqrtf(fminf(best, BIGF));
            d2p = dt * dt;
        }
        if (fl_t) {
            unsigned iv = (tv > 0.5f) ? 0xFFFFFFFFu : 0u;
            float best = col_min(&lmask[1][0][0], y, x, iv);
            float dt = sqrtf(fminf(best, BIGF));
            d2t = dt * dt;
        }
        lsum += errsq * (d2p + d2t);
    }

    // block reduce: wave64 shuffle then LDS across 4 waves
    #pragma unroll
    for (int off = 32; off > 0; off >>= 1)
        lsum += __shfl_down(lsum, off, 64);
    __shared__ float wsum[4];
    if ((tid & 63) == 0) wsum[tid >> 6] = lsum;
    __syncthreads();
    if (tid == 0) {
        float s2 = wsum[0] + wsum[1] + wsum[2] + wsum[3];
        atomicAdd(&acc[(blk & 7) * ACC_STRIDE], (double)s2);
        __threadfence();
        if (atomicAdd(cnt, 1u) == MAIN_GRID - 1) {
            double v = 0.0;
            #pragma unroll
            for (int i = 0; i < 8; ++i)
                v += atomicAdd(&acc[i * ACC_STRIDE], 0.0);  // device-coherent reads
            out[0] = (float)(v * (1.0 / (double)NPIX));
        }
    }
}

extern "C" void kernel_launch(void* const* d_in, const int* in_sizes, int n_in,
                              void* d_out, int out_size, void* d_ws, size_t ws_size,
                              hipStream_t stream) {
    const float* pred = (const float*)d_in[0];
    const float* tgt = (const float*)d_in[1];
    float* out = (float*)d_out;
    char* ws = (char*)d_ws;
    double* acc = (double*)(ws + WS_ACC_OFF);
    unsigned* cnt = (unsigned*)(ws + WS_CNT_OFF);
    unsigned* gmask = (unsigned*)(ws + WS_MASK_OFF);

    hdt_masks_kernel<<<64, 256, 0, stream>>>(pred, tgt, gmask, acc, cnt);
    hdt_main_kernel<<<MAIN_GRID, 256, 0, stream>>>(pred, tgt, gmask, acc, cnt, out);
}